// Round 1
// baseline (498.745 us; speedup 1.0000x reference)
//
#include <hip/hip_runtime.h>
#include <hip/hip_bf16.h>

typedef __attribute__((ext_vector_type(8))) __bf16 bf16x8;
typedef __attribute__((ext_vector_type(4))) float f32x4;

#define B_ROWS 16384
#define LDF 2560

__device__ __forceinline__ void async16(void* lds, const void* g) {
  __builtin_amdgcn_global_load_lds(
      (const __attribute__((address_space(1))) unsigned int*)g,
      (__attribute__((address_space(3))) unsigned int*)lds, 16, 0, 0);
}

__device__ __forceinline__ bf16x8 cvt8(float4 a, float4 b) {
  bf16x8 t;
  t[0] = (__bf16)a.x; t[1] = (__bf16)a.y; t[2] = (__bf16)a.z; t[3] = (__bf16)a.w;
  t[4] = (__bf16)b.x; t[5] = (__bf16)b.y; t[6] = (__bf16)b.z; t[7] = (__bf16)b.w;
  return t;
}

// C = A(bf16,[B_ROWS,LDF]) x W(bf16,[Ntot,Kd] row-major)^T + bias
// if relu_stats: ReLU, write h fp32, accumulate column sum/sumsq
__global__ __launch_bounds__(256) void gemm_bn(
    const __bf16* __restrict__ A,
    const __bf16* __restrict__ W,
    const float* __restrict__ bias,
    float* __restrict__ C,
    int Kd, int ldc,
    float* __restrict__ colsum, float* __restrict__ colsumsq, int relu_stats)
{
  __shared__ __bf16 At[128 * 32];
  __shared__ __bf16 Bt[128 * 32];
  __shared__ float lsum[128], lsq[128];

  const int tid  = threadIdx.x;
  const int wid  = tid >> 6;
  const int lane = tid & 63;
  const int wm   = wid >> 1, wn = wid & 1;
  const int bn0  = blockIdx.x * 128;
  const int bm0  = blockIdx.y * 128;

  if (relu_stats && tid < 128) { lsum[tid] = 0.f; lsq[tid] = 0.f; }

  f32x4 acc[4][4] = {};

  for (int kk = 0; kk < Kd; kk += 32) {
    __syncthreads();
#pragma unroll
    for (int j = 0; j < 2; ++j) {
      int f = j * 256 + tid;
      const __bf16* g = A + (size_t)(bm0 + (f >> 2)) * LDF + kk + (f & 3) * 8;
      async16((void*)(At + (size_t)(j * 256 + wid * 64) * 8), g);
    }
#pragma unroll
    for (int j = 0; j < 2; ++j) {
      int f = j * 256 + tid;
      const __bf16* g = W + (size_t)(bn0 + (f >> 2)) * Kd + kk + (f & 3) * 8;
      async16((void*)(Bt + (size_t)(j * 256 + wid * 64) * 8), g);
    }
    __syncthreads();

    bf16x8 af[4], bfr[4];
#pragma unroll
    for (int i = 0; i < 4; ++i)
      af[i] = *(const bf16x8*)(At + (wm * 64 + i * 16 + (lane & 15)) * 32 + (lane >> 4) * 8);
#pragma unroll
    for (int i = 0; i < 4; ++i)
      bfr[i] = *(const bf16x8*)(Bt + (wn * 64 + i * 16 + (lane & 15)) * 32 + (lane >> 4) * 8);
#pragma unroll
    for (int mi = 0; mi < 4; ++mi)
#pragma unroll
      for (int ni = 0; ni < 4; ++ni)
        acc[mi][ni] = __builtin_amdgcn_mfma_f32_16x16x32_bf16(af[mi], bfr[ni], acc[mi][ni], 0, 0, 0);
  }

  float psum[4] = {0.f, 0.f, 0.f, 0.f}, psq[4] = {0.f, 0.f, 0.f, 0.f};
#pragma unroll
  for (int mi = 0; mi < 4; ++mi) {
#pragma unroll
    for (int ni = 0; ni < 4; ++ni) {
      const int row0 = bm0 + wm * 64 + mi * 16 + ((lane >> 4) << 2);
      const int col  = bn0 + wn * 64 + ni * 16 + (lane & 15);
      const float bv = bias[col];
      float* cp = C + (size_t)row0 * ldc + col;
#pragma unroll
      for (int r = 0; r < 4; ++r) {
        float v = acc[mi][ni][r] + bv;
        if (relu_stats) {
          v = fmaxf(v, 0.f);
          psum[ni] += v;
          psq[ni] += v * v;
        }
        cp[(size_t)r * ldc] = v;
      }
    }
  }

  if (relu_stats) {
#pragma unroll
    for (int ni = 0; ni < 4; ++ni) {
      int cl = wn * 64 + ni * 16 + (lane & 15);
      atomicAdd(&lsum[cl], psum[ni]);
      atomicAdd(&lsq[cl], psq[ni]);
    }
    __syncthreads();
    if (tid < 128) {
      atomicAdd(&colsum[bn0 + tid], lsum[tid]);
      atomicAdd(&colsumsq[bn0 + tid], lsq[tid]);
    }
  }
}

__global__ void cast_x_kernel(const float* __restrict__ x, __bf16* __restrict__ feats) {
  int idx = blockIdx.x * blockDim.x + threadIdx.x;  // B_ROWS*64 threads
  int row = idx >> 6, c8 = (idx & 63) << 3;
  const float4* xp = (const float4*)(x + (size_t)row * 512 + c8);
  float4 a = xp[0], b = xp[1];
  *(bf16x8*)(feats + (size_t)row * LDF + c8) = cvt8(a, b);
}

__global__ void cast_w_kernel(const float* __restrict__ w, __bf16* __restrict__ o, int n8) {
  int idx = blockIdx.x * blockDim.x + threadIdx.x;
  if (idx >= n8) return;
  const float4* p = (const float4*)(w + (size_t)idx * 8);
  float4 a = p[0], b = p[1];
  *(bf16x8*)(o + (size_t)idx * 8) = cvt8(a, b);
}

__global__ void bn_finalize_kernel(const float* __restrict__ colsum,
                                   const float* __restrict__ colsumsq,
                                   const float* __restrict__ gamma,
                                   const float* __restrict__ beta,
                                   float* __restrict__ scsh) {
  int c = threadIdx.x;  // 256
  const float invB = 1.0f / 16384.0f;
  float mu  = colsum[c] * invB;
  float var = colsumsq[c] * invB - mu * mu;
  float sc  = gamma[c] * rsqrtf(var + 1e-5f);
  scsh[c] = sc;
  scsh[256 + c] = beta[c] - mu * sc;
}

__global__ void bn_apply_kernel(const float* __restrict__ h,
                                const float* __restrict__ scsh,
                                __bf16* __restrict__ feats, int colOff) {
  int idx = blockIdx.x * blockDim.x + threadIdx.x;  // B_ROWS*32 threads
  int row = idx >> 5, c8 = (idx & 31) << 3;
  const float4* hp = (const float4*)(h + (size_t)row * 256 + c8);
  float4 a = hp[0], b = hp[1];
  const float4* scp = (const float4*)(scsh + c8);
  float4 s0 = scp[0], s1 = scp[1];
  const float4* shp = (const float4*)(scsh + 256 + c8);
  float4 t0 = shp[0], t1 = shp[1];
  float4 r0, r1;
  r0.x = fmaf(a.x, s0.x, t0.x); r0.y = fmaf(a.y, s0.y, t0.y);
  r0.z = fmaf(a.z, s0.z, t0.z); r0.w = fmaf(a.w, s0.w, t0.w);
  r1.x = fmaf(b.x, s1.x, t1.x); r1.y = fmaf(b.y, s1.y, t1.y);
  r1.z = fmaf(b.z, s1.z, t1.z); r1.w = fmaf(b.w, s1.w, t1.w);
  *(bf16x8*)(feats + (size_t)row * LDF + colOff + c8) = cvt8(r0, r1);
}

extern "C" void kernel_launch(void* const* d_in, const int* in_sizes, int n_in,
                              void* d_out, int out_size, void* d_ws, size_t ws_size,
                              hipStream_t stream) {
  const float* x = (const float*)d_in[0];
  const float* Wi[8];
  for (int i = 0; i < 8; ++i) Wi[i] = (const float*)d_in[1 + i];
  const float* b     = (const float*)d_in[9];
  const float* gamma = (const float*)d_in[10];
  const float* beta  = (const float*)d_in[11];
  const float* Wout  = (const float*)d_in[12];
  const float* bout  = (const float*)d_in[13];
  float* out = (float*)d_out;

  char* ws = (char*)d_ws;
  __bf16* feats = (__bf16*)ws;
  size_t off = (size_t)B_ROWS * LDF * 2;
  __bf16* wb[8];
  {
    int d = 512;
    for (int i = 0; i < 8; ++i) { wb[i] = (__bf16*)(ws + off); off += (size_t)256 * d * 2; d += 256; }
  }
  __bf16* woutb = (__bf16*)(ws + off); off += (size_t)128 * 2560 * 2;
  float* h = (float*)(ws + off); off += (size_t)B_ROWS * 256 * 4;
  float* colsum   = (float*)(ws + off); off += 8 * 256 * 4;
  float* colsumsq = (float*)(ws + off); off += 8 * 256 * 4;
  float* scsh     = (float*)(ws + off); off += 2 * 256 * 4;

  hipMemsetAsync(colsum, 0, 2 * 8 * 256 * 4, stream);

  cast_x_kernel<<<B_ROWS * 64 / 256, 256, 0, stream>>>(x, feats);
  {
    int d = 512;
    for (int i = 0; i < 8; ++i) {
      int n8 = 256 * d / 8;
      cast_w_kernel<<<(n8 + 255) / 256, 256, 0, stream>>>(Wi[i], wb[i], n8);
      d += 256;
    }
    int n8 = 128 * 2560 / 8;
    cast_w_kernel<<<(n8 + 255) / 256, 256, 0, stream>>>(Wout, woutb, n8);
  }

  int d = 512;
  for (int i = 0; i < 8; ++i) {
    gemm_bn<<<dim3(2, 128), 256, 0, stream>>>(feats, wb[i], b + i * 256, h, d, 256,
                                              colsum + i * 256, colsumsq + i * 256, 1);
    bn_finalize_kernel<<<1, 256, 0, stream>>>(colsum + i * 256, colsumsq + i * 256,
                                              gamma + i * 256, beta + i * 256, scsh);
    bn_apply_kernel<<<B_ROWS * 32 / 256, 256, 0, stream>>>(h, scsh, feats, d);
    d += 256;
  }
  gemm_bn<<<dim3(1, 128), 256, 0, stream>>>(feats, woutb, bout, out, 2560, 128,
                                            nullptr, nullptr, 0);
}

// Round 2
// 443.921 us; speedup vs baseline: 1.1235x; 1.1235x over previous
//
#include <hip/hip_runtime.h>
#include <hip/hip_bf16.h>

typedef __attribute__((ext_vector_type(8))) __bf16 bf16x8;
typedef __attribute__((ext_vector_type(4))) float f32x4;

#define B_ROWS 16384
#define LDF 2560

__device__ __forceinline__ void async16(void* lds, const void* g) {
  __builtin_amdgcn_global_load_lds(
      (const __attribute__((address_space(1))) unsigned int*)g,
      (__attribute__((address_space(3))) unsigned int*)lds, 16, 0, 0);
}

__device__ __forceinline__ bf16x8 cvt8(float4 a, float4 b) {
  bf16x8 t;
  t[0] = (__bf16)a.x; t[1] = (__bf16)a.y; t[2] = (__bf16)a.z; t[3] = (__bf16)a.w;
  t[4] = (__bf16)b.x; t[5] = (__bf16)b.y; t[6] = (__bf16)b.z; t[7] = (__bf16)b.w;
  return t;
}

// C = A(bf16,[B_ROWS,LDF]) x W(bf16,[Ntot,Kd] row-major)^T + bias
// Tile: BM=64 x BN=64, 4 waves (2x2), each wave a 32x32 quadrant.
// LDS layout is k-slot-swizzled via pre-swizzled global source (linear dest).
__global__ __launch_bounds__(256) void gemm_bn(
    const __bf16* __restrict__ A,
    const __bf16* __restrict__ W,
    const float* __restrict__ bias,
    float* __restrict__ C,
    int Kd, int ldc,
    float* __restrict__ colsum, float* __restrict__ colsumsq, int relu_stats)
{
  __shared__ __bf16 At[64 * 32];
  __shared__ __bf16 Bt[64 * 32];
  __shared__ float lsum[64], lsq[64];

  const int tid  = threadIdx.x;
  const int wid  = tid >> 6;
  const int lane = tid & 63;
  const int wm   = wid >> 1, wn = wid & 1;
  const int bn0  = blockIdx.x * 64;
  const int bm0  = blockIdx.y * 64;

  if (relu_stats && tid < 64) { lsum[tid] = 0.f; lsq[tid] = 0.f; }

  // staging: thread tid -> LDS row = tid>>2, slot = tid&3 (linear dest = tid*16B)
  // source k-chunk is swizzled so that LDS[row][slot] holds ko = slot ^ ((row>>2)&3)
  const int srow = tid >> 2;
  const int sko  = (tid & 3) ^ ((srow >> 2) & 3);
  const __bf16* aSrc = A + (size_t)(bm0 + srow) * LDF + sko * 8;
  const __bf16* bSrc = W + (size_t)(bn0 + srow) * Kd + sko * 8;

  f32x4 acc[2][2] = {};

  // fragment rows (fixed per thread)
  const int fr = lane & 15;          // row-in-16 of fragment
  const int fk = lane >> 4;          // logical k-slot 0..3

  for (int kk = 0; kk < Kd; kk += 32) {
    __syncthreads();
    async16((void*)(At + (size_t)tid * 8), aSrc + kk);
    async16((void*)(Bt + (size_t)tid * 8), bSrc + kk);
    __syncthreads();

    bf16x8 af[2], bfr[2];
#pragma unroll
    for (int i = 0; i < 2; ++i) {
      int r = wm * 32 + i * 16 + fr;
      int ss = fk ^ ((r >> 2) & 3);
      af[i] = *(const bf16x8*)(At + r * 32 + ss * 8);
    }
#pragma unroll
    for (int i = 0; i < 2; ++i) {
      int r = wn * 32 + i * 16 + fr;
      int ss = fk ^ ((r >> 2) & 3);
      bfr[i] = *(const bf16x8*)(Bt + r * 32 + ss * 8);
    }
#pragma unroll
    for (int mi = 0; mi < 2; ++mi)
#pragma unroll
      for (int ni = 0; ni < 2; ++ni)
        acc[mi][ni] = __builtin_amdgcn_mfma_f32_16x16x32_bf16(af[mi], bfr[ni], acc[mi][ni], 0, 0, 0);
  }

  float psum[2] = {0.f, 0.f}, psq[2] = {0.f, 0.f};
#pragma unroll
  for (int mi = 0; mi < 2; ++mi) {
#pragma unroll
    for (int ni = 0; ni < 2; ++ni) {
      const int row0 = bm0 + wm * 32 + mi * 16 + (fk << 2);
      const int col  = bn0 + wn * 32 + ni * 16 + fr;
      const float bv = bias[col];
      float* cp = C + (size_t)row0 * ldc + col;
#pragma unroll
      for (int r = 0; r < 4; ++r) {
        float v = acc[mi][ni][r] + bv;
        if (relu_stats) {
          v = fmaxf(v, 0.f);
          psum[ni] += v;
          psq[ni] += v * v;
        }
        cp[(size_t)r * ldc] = v;
      }
    }
  }

  if (relu_stats) {
#pragma unroll
    for (int ni = 0; ni < 2; ++ni) {
      int cl = wn * 32 + ni * 16 + fr;
      atomicAdd(&lsum[cl], psum[ni]);
      atomicAdd(&lsq[cl], psq[ni]);
    }
    __syncthreads();
    if (tid < 64) {
      atomicAdd(&colsum[bn0 + tid], lsum[tid]);
      atomicAdd(&colsumsq[bn0 + tid], lsq[tid]);
    }
  }
}

__global__ void cast_x_kernel(const float* __restrict__ x, __bf16* __restrict__ feats) {
  int idx = blockIdx.x * blockDim.x + threadIdx.x;  // B_ROWS*64 threads
  int row = idx >> 6, c8 = (idx & 63) << 3;
  const float4* xp = (const float4*)(x + (size_t)row * 512 + c8);
  float4 a = xp[0], b = xp[1];
  *(bf16x8*)(feats + (size_t)row * LDF + c8) = cvt8(a, b);
}

__global__ void cast_w_kernel(const float* __restrict__ w, __bf16* __restrict__ o, int n8) {
  int idx = blockIdx.x * blockDim.x + threadIdx.x;
  if (idx >= n8) return;
  const float4* p = (const float4*)(w + (size_t)idx * 8);
  float4 a = p[0], b = p[1];
  *(bf16x8*)(o + (size_t)idx * 8) = cvt8(a, b);
}

__global__ void bn_finalize_kernel(const float* __restrict__ colsum,
                                   const float* __restrict__ colsumsq,
                                   const float* __restrict__ gamma,
                                   const float* __restrict__ beta,
                                   float* __restrict__ scsh) {
  int c = threadIdx.x;  // 256
  const float invB = 1.0f / 16384.0f;
  float mu  = colsum[c] * invB;
  float var = colsumsq[c] * invB - mu * mu;
  float sc  = gamma[c] * rsqrtf(var + 1e-5f);
  scsh[c] = sc;
  scsh[256 + c] = beta[c] - mu * sc;
}

__global__ void bn_apply_kernel(const float* __restrict__ h,
                                const float* __restrict__ scsh,
                                __bf16* __restrict__ feats, int colOff) {
  int idx = blockIdx.x * blockDim.x + threadIdx.x;  // B_ROWS*32 threads
  int row = idx >> 5, c8 = (idx & 31) << 3;
  const float4* hp = (const float4*)(h + (size_t)row * 256 + c8);
  float4 a = hp[0], b = hp[1];
  const float4* scp = (const float4*)(scsh + c8);
  float4 s0 = scp[0], s1 = scp[1];
  const float4* shp = (const float4*)(scsh + 256 + c8);
  float4 t0 = shp[0], t1 = shp[1];
  float4 r0, r1;
  r0.x = fmaf(a.x, s0.x, t0.x); r0.y = fmaf(a.y, s0.y, t0.y);
  r0.z = fmaf(a.z, s0.z, t0.z); r0.w = fmaf(a.w, s0.w, t0.w);
  r1.x = fmaf(b.x, s1.x, t1.x); r1.y = fmaf(b.y, s1.y, t1.y);
  r1.z = fmaf(b.z, s1.z, t1.z); r1.w = fmaf(b.w, s1.w, t1.w);
  *(bf16x8*)(feats + (size_t)row * LDF + colOff + c8) = cvt8(r0, r1);
}

extern "C" void kernel_launch(void* const* d_in, const int* in_sizes, int n_in,
                              void* d_out, int out_size, void* d_ws, size_t ws_size,
                              hipStream_t stream) {
  const float* x = (const float*)d_in[0];
  const float* Wi[8];
  for (int i = 0; i < 8; ++i) Wi[i] = (const float*)d_in[1 + i];
  const float* b     = (const float*)d_in[9];
  const float* gamma = (const float*)d_in[10];
  const float* beta  = (const float*)d_in[11];
  const float* Wout  = (const float*)d_in[12];
  const float* bout  = (const float*)d_in[13];
  float* out = (float*)d_out;

  char* ws = (char*)d_ws;
  __bf16* feats = (__bf16*)ws;
  size_t off = (size_t)B_ROWS * LDF * 2;
  __bf16* wb[8];
  {
    int d = 512;
    for (int i = 0; i < 8; ++i) { wb[i] = (__bf16*)(ws + off); off += (size_t)256 * d * 2; d += 256; }
  }
  __bf16* woutb = (__bf16*)(ws + off); off += (size_t)128 * 2560 * 2;
  float* h = (float*)(ws + off); off += (size_t)B_ROWS * 256 * 4;
  float* colsum   = (float*)(ws + off); off += 8 * 256 * 4;
  float* colsumsq = (float*)(ws + off); off += 8 * 256 * 4;
  float* scsh     = (float*)(ws + off); off += 2 * 256 * 4;

  hipMemsetAsync(colsum, 0, 2 * 8 * 256 * 4, stream);

  cast_x_kernel<<<B_ROWS * 64 / 256, 256, 0, stream>>>(x, feats);
  {
    int d = 512;
    for (int i = 0; i < 8; ++i) {
      int n8 = 256 * d / 8;
      cast_w_kernel<<<(n8 + 255) / 256, 256, 0, stream>>>(Wi[i], wb[i], n8);
      d += 256;
    }
    int n8 = 128 * 2560 / 8;
    cast_w_kernel<<<(n8 + 255) / 256, 256, 0, stream>>>(Wout, woutb, n8);
  }

  int d = 512;
  for (int i = 0; i < 8; ++i) {
    gemm_bn<<<dim3(4, 256), 256, 0, stream>>>(feats, wb[i], b + i * 256, h, d, 256,
                                              colsum + i * 256, colsumsq + i * 256, 1);
    bn_finalize_kernel<<<1, 256, 0, stream>>>(colsum + i * 256, colsumsq + i * 256,
                                              gamma + i * 256, beta + i * 256, scsh);
    bn_apply_kernel<<<B_ROWS * 32 / 256, 256, 0, stream>>>(h, scsh, feats, d);
    d += 256;
  }
  gemm_bn<<<dim3(2, 256), 256, 0, stream>>>(feats, woutb, bout, out, 2560, 128,
                                            nullptr, nullptr, 0);
}

// Round 3
// 381.530 us; speedup vs baseline: 1.3072x; 1.1635x over previous
//
#include <hip/hip_runtime.h>
#include <hip/hip_bf16.h>

typedef __attribute__((ext_vector_type(8))) __bf16 bf16x8;
typedef __attribute__((ext_vector_type(4))) float f32x4;

#define B_ROWS 16384
#define LDF 2560
#define BN_EPS 1e-5f

__device__ __forceinline__ void async16(void* lds, const void* g) {
  __builtin_amdgcn_global_load_lds(
      (const __attribute__((address_space(1))) unsigned int*)g,
      (__attribute__((address_space(3))) unsigned int*)lds, 16, 0, 0);
}

__device__ __forceinline__ bf16x8 cvt8(float4 a, float4 b) {
  bf16x8 t;
  t[0] = (__bf16)a.x; t[1] = (__bf16)a.y; t[2] = (__bf16)a.z; t[3] = (__bf16)a.w;
  t[4] = (__bf16)b.x; t[5] = (__bf16)b.y; t[6] = (__bf16)b.z; t[7] = (__bf16)b.w;
  return t;
}

// Tile BM=64 x BN=128, BK=64, 4 waves (2x2), wave = 32 rows x 64 cols.
// 2-phase double-buffered LDS; stats via shfl_xor + global atomics.
// mode 1: h = ReLU(A W^T + bias) -> bf16 into hout (stride LDF), accumulate col stats.
// mode 0: fout = A W^T + bias (fp32, ldc=128).
__global__ __launch_bounds__(256) void gemm_stage(
    const __bf16* __restrict__ A, const __bf16* __restrict__ W,
    const float* __restrict__ bias,
    __bf16* __restrict__ hout, float* __restrict__ fout,
    int Kd, float* __restrict__ colsum, float* __restrict__ colsumsq, int mode)
{
  __shared__ __bf16 At[2][64 * 64];
  __shared__ __bf16 Bt[2][128 * 64];

  const int tid  = threadIdx.x;
  const int lane = tid & 63;
  const int wid  = tid >> 6;
  const int wm   = wid >> 1, wn = wid & 1;
  const int bn0  = blockIdx.x * 128;
  const int bm0  = blockIdx.y * 64;
  const int fr   = lane & 15, fk = lane >> 4;

  // staging: thread t, chunk j: LDS linear elem (j*256+t)*8; row=(j*256+t)>>3, slot=t&7
  // source k-chunk pre-swizzled: sko = slot ^ (row&7)  (row&7 identical across j)
  const int srow = tid >> 3;
  const int sko  = (tid & 7) ^ (srow & 7);
  const __bf16* aS0 = A + (size_t)(bm0 + srow) * LDF + sko * 8;
  const __bf16* aS1 = A + (size_t)(bm0 + 32 + srow) * LDF + sko * 8;
  const __bf16* bS0 = W + (size_t)(bn0 + srow) * Kd + sko * 8;
  const __bf16* bS1 = W + (size_t)(bn0 + 32 + srow) * Kd + sko * 8;
  const __bf16* bS2 = W + (size_t)(bn0 + 64 + srow) * Kd + sko * 8;
  const __bf16* bS3 = W + (size_t)(bn0 + 96 + srow) * Kd + sko * 8;

#define STAGE(buf, kt) do {                                          \
    async16((void*)(&At[buf][(size_t)tid * 8]),         aS0 + (kt)); \
    async16((void*)(&At[buf][(size_t)(256 + tid) * 8]), aS1 + (kt)); \
    async16((void*)(&Bt[buf][(size_t)tid * 8]),         bS0 + (kt)); \
    async16((void*)(&Bt[buf][(size_t)(256 + tid) * 8]), bS1 + (kt)); \
    async16((void*)(&Bt[buf][(size_t)(512 + tid) * 8]), bS2 + (kt)); \
    async16((void*)(&Bt[buf][(size_t)(768 + tid) * 8]), bS3 + (kt)); \
  } while (0)

  f32x4 acc[2][4] = {};

  STAGE(0, 0);
  __syncthreads();

  int cur = 0;
  for (int kk = 0; kk < Kd; kk += 64) {
    if (kk + 64 < Kd) STAGE(cur ^ 1, kk + 64);
#pragma unroll
    for (int ksub = 0; ksub < 2; ++ksub) {
      const int kc = ksub * 4 + fk;
      bf16x8 af[2], bf[4];
#pragma unroll
      for (int mi = 0; mi < 2; ++mi) {
        int r = wm * 32 + mi * 16 + fr;
        af[mi] = *(const bf16x8*)(&At[cur][r * 64 + (kc ^ (r & 7)) * 8]);
      }
#pragma unroll
      for (int ni = 0; ni < 4; ++ni) {
        int r = wn * 64 + ni * 16 + fr;
        bf[ni] = *(const bf16x8*)(&Bt[cur][r * 64 + (kc ^ (r & 7)) * 8]);
      }
#pragma unroll
      for (int mi = 0; mi < 2; ++mi)
#pragma unroll
        for (int ni = 0; ni < 4; ++ni)
          acc[mi][ni] = __builtin_amdgcn_mfma_f32_16x16x32_bf16(af[mi], bf[ni], acc[mi][ni], 0, 0, 0);
    }
    __syncthreads();
    cur ^= 1;
  }
#undef STAGE

  if (mode) {
    float psum[4] = {0.f, 0.f, 0.f, 0.f}, psq[4] = {0.f, 0.f, 0.f, 0.f};
#pragma unroll
    for (int mi = 0; mi < 2; ++mi) {
#pragma unroll
      for (int ni = 0; ni < 4; ++ni) {
        const int col  = bn0 + wn * 64 + ni * 16 + fr;
        const int row0 = bm0 + wm * 32 + mi * 16 + fk * 4;
        const float bv = bias[col];
        __bf16* hp = hout + (size_t)row0 * LDF + col;
#pragma unroll
        for (int r = 0; r < 4; ++r) {
          float v = fmaxf(acc[mi][ni][r] + bv, 0.f);
          psum[ni] += v; psq[ni] += v * v;
          hp[(size_t)r * LDF] = (__bf16)v;
        }
      }
    }
#pragma unroll
    for (int ni = 0; ni < 4; ++ni) {
      float s = psum[ni], q = psq[ni];
      s += __shfl_xor(s, 16); s += __shfl_xor(s, 32);
      q += __shfl_xor(q, 16); q += __shfl_xor(q, 32);
      if (fk == 0) {
        int col = bn0 + wn * 64 + ni * 16 + fr;
        atomicAdd(&colsum[col], s);
        atomicAdd(&colsumsq[col], q);
      }
    }
  } else {
#pragma unroll
    for (int mi = 0; mi < 2; ++mi) {
#pragma unroll
      for (int ni = 0; ni < 4; ++ni) {
        const int col  = bn0 + wn * 64 + ni * 16 + fr;
        const int row0 = bm0 + wm * 32 + mi * 16 + fk * 4;
        const float bv = bias[col];
        float* cp = fout + (size_t)row0 * 128 + col;
#pragma unroll
        for (int r = 0; r < 4; ++r)
          cp[(size_t)r * 128] = acc[mi][ni][r] + bv;
      }
    }
  }
}

__global__ void cast_x_kernel(const float* __restrict__ x, __bf16* __restrict__ feats) {
  int idx = blockIdx.x * blockDim.x + threadIdx.x;  // B_ROWS*64 threads
  int row = idx >> 6, c8 = (idx & 63) << 3;
  const float4* xp = (const float4*)(x + (size_t)row * 512 + c8);
  float4 a = xp[0], b = xp[1];
  *(bf16x8*)(feats + (size_t)row * LDF + c8) = cvt8(a, b);
}

struct WJobs { const float* src[9]; __bf16* dst[9]; int n8[9]; };

__global__ void cast_w_all(WJobs jobs, int total8) {
  int idx = blockIdx.x * blockDim.x + threadIdx.x;
  if (idx >= total8) return;
  int j = 0, off = idx;
  while (off >= jobs.n8[j]) { off -= jobs.n8[j]; ++j; }
  const float4* p = (const float4*)(jobs.src[j] + (size_t)off * 8);
  float4 a = p[0], b = p[1];
  *(bf16x8*)(jobs.dst[j] + (size_t)off * 8) = cvt8(a, b);
}

// In-place BN apply with finalize folded in: f[row][c] = (f - mu)*gamma*rsqrt(var+eps) + beta
__global__ void bn_apply_kernel(__bf16* __restrict__ f,
                                const float* __restrict__ colsum,
                                const float* __restrict__ colsumsq,
                                const float* __restrict__ gamma,
                                const float* __restrict__ beta) {
  int idx = blockIdx.x * blockDim.x + threadIdx.x;  // B_ROWS*32 threads
  int row = idx >> 5, c8 = (idx & 31) << 3;
  const float invB = 1.0f / 16384.0f;
  bf16x8 v = *(const bf16x8*)(f + (size_t)row * LDF + c8);
  bf16x8 o;
#pragma unroll
  for (int i = 0; i < 8; ++i) {
    float mu  = colsum[c8 + i] * invB;
    float var = colsumsq[c8 + i] * invB - mu * mu;
    float sc  = gamma[c8 + i] * rsqrtf(var + BN_EPS);
    float sh  = beta[c8 + i] - mu * sc;
    o[i] = (__bf16)fmaf((float)v[i], sc, sh);
  }
  *(bf16x8*)(f + (size_t)row * LDF + c8) = o;
}

extern "C" void kernel_launch(void* const* d_in, const int* in_sizes, int n_in,
                              void* d_out, int out_size, void* d_ws, size_t ws_size,
                              hipStream_t stream) {
  const float* x = (const float*)d_in[0];
  const float* Wi[8];
  for (int i = 0; i < 8; ++i) Wi[i] = (const float*)d_in[1 + i];
  const float* b     = (const float*)d_in[9];
  const float* gamma = (const float*)d_in[10];
  const float* beta  = (const float*)d_in[11];
  const float* Wout  = (const float*)d_in[12];
  const float* bout  = (const float*)d_in[13];
  float* out = (float*)d_out;

  char* ws = (char*)d_ws;
  __bf16* feats = (__bf16*)ws;
  size_t off = (size_t)B_ROWS * LDF * 2;
  __bf16* wb[8];
  {
    int d = 512;
    for (int i = 0; i < 8; ++i) { wb[i] = (__bf16*)(ws + off); off += (size_t)256 * d * 2; d += 256; }
  }
  __bf16* woutb = (__bf16*)(ws + off); off += (size_t)128 * 2560 * 2;
  float* colsum   = (float*)(ws + off); off += 8 * 256 * 4;
  float* colsumsq = (float*)(ws + off); off += 8 * 256 * 4;

  hipMemsetAsync(colsum, 0, 2 * 8 * 256 * 4, stream);

  cast_x_kernel<<<B_ROWS * 64 / 256, 256, 0, stream>>>(x, feats);

  WJobs jobs; int total8 = 0;
  {
    int d = 512;
    for (int i = 0; i < 8; ++i) {
      jobs.src[i] = Wi[i]; jobs.dst[i] = wb[i]; jobs.n8[i] = 256 * d / 8;
      total8 += jobs.n8[i]; d += 256;
    }
    jobs.src[8] = Wout; jobs.dst[8] = woutb; jobs.n8[8] = 128 * 2560 / 8;
    total8 += jobs.n8[8];
  }
  cast_w_all<<<(total8 + 255) / 256, 256, 0, stream>>>(jobs, total8);

  int d = 512;
  for (int i = 0; i < 8; ++i) {
    gemm_stage<<<dim3(2, 256), 256, 0, stream>>>(feats, wb[i], b + i * 256,
                                                 feats + d, nullptr, d,
                                                 colsum + i * 256, colsumsq + i * 256, 1);
    bn_apply_kernel<<<B_ROWS * 32 / 256, 256, 0, stream>>>(feats + d,
                                                           colsum + i * 256, colsumsq + i * 256,
                                                           gamma + i * 256, beta + i * 256);
    d += 256;
  }
  gemm_stage<<<dim3(1, 256), 256, 0, stream>>>(feats, woutb, bout,
                                               nullptr, out, 2560, nullptr, nullptr, 0);
}

// Round 4
// 365.945 us; speedup vs baseline: 1.3629x; 1.0426x over previous
//
#include <hip/hip_runtime.h>
#include <hip/hip_bf16.h>

typedef __attribute__((ext_vector_type(8))) __bf16 bf16x8;
typedef __attribute__((ext_vector_type(4))) __bf16 bf16x4;
typedef __attribute__((ext_vector_type(4))) float f32x4;

#define B_ROWS 16384
#define LDF 2560
#define BN_EPS 1e-5f

__device__ __forceinline__ void async16(void* lds, const void* g) {
  __builtin_amdgcn_global_load_lds(
      (const __attribute__((address_space(1))) unsigned int*)g,
      (__attribute__((address_space(3))) unsigned int*)lds, 16, 0, 0);
}

__device__ __forceinline__ bf16x8 cvt8(float4 a, float4 b) {
  bf16x8 t;
  t[0] = (__bf16)a.x; t[1] = (__bf16)a.y; t[2] = (__bf16)a.z; t[3] = (__bf16)a.w;
  t[4] = (__bf16)b.x; t[5] = (__bf16)b.y; t[6] = (__bf16)b.z; t[7] = (__bf16)b.w;
  return t;
}

// C = A(bf16,[B_ROWS,LDF]) x W(bf16,[Ntot,Kd])^T + badj
// Tile BM=128 x BN=128, BK=64, 4 waves (2x2), wave-tile 64x64 (acc 4x4).
// 3-buffer LDS pipeline, counted vmcnt (never 0 in steady state), raw barriers.
// mode 1: ReLU -> bf16 into hout (stride LDF) + col sum/sumsq atomics.
// mode 0: fp32 into fout (ldc=128).
__global__ __launch_bounds__(256, 1) void gemm_stage(
    const __bf16* __restrict__ A, const __bf16* __restrict__ W,
    const float* __restrict__ badj,
    __bf16* __restrict__ hout, float* __restrict__ fout,
    int Kd, float* __restrict__ colsum, float* __restrict__ colsumsq, int mode)
{
  __shared__ __bf16 At[3][128 * 64];
  __shared__ __bf16 Bt[3][128 * 64];

  const int tid  = threadIdx.x;
  const int lane = tid & 63;
  const int wid  = tid >> 6;
  const int wm   = wid >> 1, wn = wid & 1;
  const int bn0  = blockIdx.x * 128;
  const int bm0  = blockIdx.y * 128;
  const int fr   = lane & 15, fk = lane >> 4;

  // staging: chunk j in 0..3, linear LDS elem (j*256+tid)*8.
  // row = j*32 + (tid>>3), slot = tid&7; source pre-swizzled: sko = slot ^ (row&7).
  const int srow = tid >> 3;
  const int sko  = (tid & 7) ^ (srow & 7);
  const __bf16* aS[4];
  const __bf16* bS[4];
#pragma unroll
  for (int j = 0; j < 4; ++j) {
    aS[j] = A + (size_t)(bm0 + j * 32 + srow) * LDF + sko * 8;
    bS[j] = W + (size_t)(bn0 + j * 32 + srow) * Kd + sko * 8;
  }

#define STAGE(b, kt) do {                                           \
    _Pragma("unroll")                                               \
    for (int j = 0; j < 4; ++j) {                                   \
      async16((void*)(&At[b][(j * 256 + tid) * 8]), aS[j] + (kt));  \
      async16((void*)(&Bt[b][(j * 256 + tid) * 8]), bS[j] + (kt));  \
    }                                                               \
  } while (0)

  f32x4 acc[4][4] = {};

  const int NT = Kd >> 6;
  STAGE(0, 0);
  STAGE(1, 64);

  int cur = 0, pre = 2;
  for (int t = 0; t < NT; ++t) {
    if (t + 2 < NT) {
      STAGE(pre, (t + 2) * 64);
      asm volatile("s_waitcnt vmcnt(16)" ::: "memory");
    } else if (t + 1 < NT) {
      asm volatile("s_waitcnt vmcnt(8)" ::: "memory");
    } else {
      asm volatile("s_waitcnt vmcnt(0)" ::: "memory");
    }
    __builtin_amdgcn_s_barrier();
    __builtin_amdgcn_sched_barrier(0);

    const __bf16* at = At[cur];
    const __bf16* bt = Bt[cur];
#pragma unroll
    for (int ksub = 0; ksub < 2; ++ksub) {
      const int kc = ksub * 4 + fk;
      bf16x8 af[4], bf[4];
#pragma unroll
      for (int mi = 0; mi < 4; ++mi) {
        int r = wm * 64 + mi * 16 + fr;
        af[mi] = *(const bf16x8*)(at + r * 64 + ((kc ^ (r & 7)) << 3));
      }
#pragma unroll
      for (int ni = 0; ni < 4; ++ni) {
        int r = wn * 64 + ni * 16 + fr;
        bf[ni] = *(const bf16x8*)(bt + r * 64 + ((kc ^ (r & 7)) << 3));
      }
#pragma unroll
      for (int mi = 0; mi < 4; ++mi)
#pragma unroll
        for (int ni = 0; ni < 4; ++ni)
          acc[mi][ni] = __builtin_amdgcn_mfma_f32_16x16x32_bf16(af[mi], bf[ni], acc[mi][ni], 0, 0, 0);
    }
    __builtin_amdgcn_sched_barrier(0);
    __builtin_amdgcn_s_barrier();

    cur = (cur == 2) ? 0 : cur + 1;
    pre = (pre == 2) ? 0 : pre + 1;
  }
#undef STAGE

  if (mode) {
    float psum[4] = {0.f, 0.f, 0.f, 0.f}, psq[4] = {0.f, 0.f, 0.f, 0.f};
#pragma unroll
    for (int mi = 0; mi < 4; ++mi) {
#pragma unroll
      for (int ni = 0; ni < 4; ++ni) {
        const int col  = bn0 + wn * 64 + ni * 16 + fr;
        const int row0 = bm0 + wm * 64 + mi * 16 + fk * 4;
        const float bv = badj[col];
        __bf16* hp = hout + (size_t)row0 * LDF + col;
#pragma unroll
        for (int r = 0; r < 4; ++r) {
          float v = fmaxf(acc[mi][ni][r] + bv, 0.f);
          psum[ni] += v; psq[ni] += v * v;
          hp[(size_t)r * LDF] = (__bf16)v;
        }
      }
    }
#pragma unroll
    for (int ni = 0; ni < 4; ++ni) {
      float s = psum[ni], q = psq[ni];
      s += __shfl_xor(s, 16); s += __shfl_xor(s, 32);
      q += __shfl_xor(q, 16); q += __shfl_xor(q, 32);
      if (fk == 0) {
        int col = bn0 + wn * 64 + ni * 16 + fr;
        atomicAdd(&colsum[col], s);
        atomicAdd(&colsumsq[col], q);
      }
    }
  } else {
#pragma unroll
    for (int mi = 0; mi < 4; ++mi) {
#pragma unroll
      for (int ni = 0; ni < 4; ++ni) {
        const int col  = bn0 + wn * 64 + ni * 16 + fr;
        const int row0 = bm0 + wm * 64 + mi * 16 + fk * 4;
        const float bv = badj[col];
        float* cp = fout + (size_t)row0 * 128 + col;
#pragma unroll
        for (int r = 0; r < 4; ++r)
          cp[(size_t)r * 128] = acc[mi][ni][r] + bv;
      }
    }
  }
}

__global__ void cast_x_kernel(const float* __restrict__ x, __bf16* __restrict__ feats) {
  int idx = blockIdx.x * blockDim.x + threadIdx.x;  // B_ROWS*64 threads
  int row = idx >> 6, c8 = (idx & 63) << 3;
  const float4* xp = (const float4*)(x + (size_t)row * 512 + c8);
  float4 a = xp[0], b = xp[1];
  *(bf16x8*)(feats + (size_t)row * LDF + c8) = cvt8(a, b);
}

// Fused: fp32->bf16 cast of W with BN folded in.
// W'[n,c] = W[n,c]*sc[c];  badj[n] = bias[n] + sum_c sh[c]*W[n,c]
// sc,sh computed on the fly from colsum/colsumsq (stages fully before this one).
__global__ void prep_w(const float* __restrict__ W, const float* __restrict__ bias,
                       const float* __restrict__ colsum, const float* __restrict__ colsumsq,
                       const float* __restrict__ gamma, const float* __restrict__ beta,
                       __bf16* __restrict__ Wb, float* __restrict__ badj, int Kd)
{
  const int n = blockIdx.x, t = threadIdx.x;  // 256 threads per row
  const float invB = 1.0f / 16384.0f;
  float accb = 0.f;
  for (int c0 = t * 4; c0 < Kd; c0 += 1024) {
    float4 w = *(const float4*)(W + (size_t)n * Kd + c0);
    float wv[4] = {w.x, w.y, w.z, w.w};
    bf16x4 o;
#pragma unroll
    for (int i = 0; i < 4; ++i) {
      int c = c0 + i;
      float sc = 1.f, sh = 0.f;
      if (c >= 512) {
        int idx = c - 512;  // stage-major [8][256] layout matches feats cols
        float mu  = colsum[idx] * invB;
        float var = colsumsq[idx] * invB - mu * mu;
        sc = gamma[idx] * rsqrtf(var + BN_EPS);
        sh = beta[idx] - mu * sc;
      }
      accb += wv[i] * sh;
      o[i] = (__bf16)(wv[i] * sc);
    }
    *(bf16x4*)(Wb + (size_t)n * Kd + c0) = o;
  }
  __shared__ float red[256];
  red[t] = accb;
  __syncthreads();
  for (int s = 128; s > 0; s >>= 1) {
    if (t < s) red[t] += red[t + s];
    __syncthreads();
  }
  if (t == 0) badj[n] = bias[n] + red[0];
}

extern "C" void kernel_launch(void* const* d_in, const int* in_sizes, int n_in,
                              void* d_out, int out_size, void* d_ws, size_t ws_size,
                              hipStream_t stream) {
  const float* x = (const float*)d_in[0];
  const float* Wi[8];
  for (int i = 0; i < 8; ++i) Wi[i] = (const float*)d_in[1 + i];
  const float* b     = (const float*)d_in[9];
  const float* gamma = (const float*)d_in[10];
  const float* beta  = (const float*)d_in[11];
  const float* Wout  = (const float*)d_in[12];
  const float* bout  = (const float*)d_in[13];
  float* out = (float*)d_out;

  char* ws = (char*)d_ws;
  __bf16* feats = (__bf16*)ws;
  size_t off = (size_t)B_ROWS * LDF * 2;
  __bf16* wb[8];
  {
    int d = 512;
    for (int i = 0; i < 8; ++i) { wb[i] = (__bf16*)(ws + off); off += (size_t)256 * d * 2; d += 256; }
  }
  __bf16* woutb = (__bf16*)(ws + off); off += (size_t)128 * 2560 * 2;
  float* colsum   = (float*)(ws + off); off += 8 * 256 * 4;
  float* colsumsq = (float*)(ws + off); off += 8 * 256 * 4;
  float* badj     = (float*)(ws + off); off += 9 * 256 * 4;

  hipMemsetAsync(colsum, 0, 2 * 8 * 256 * 4, stream);

  cast_x_kernel<<<B_ROWS * 64 / 256, 256, 0, stream>>>(x, feats);

  int d = 512;
  for (int i = 0; i < 8; ++i) {
    prep_w<<<256, 256, 0, stream>>>(Wi[i], b + i * 256, colsum, colsumsq,
                                    gamma, beta, wb[i], badj + i * 256, d);
    gemm_stage<<<dim3(2, 128), 256, 0, stream>>>(feats, wb[i], badj + i * 256,
                                                 feats + d, nullptr, d,
                                                 colsum + i * 256, colsumsq + i * 256, 1);
    d += 256;
  }
  prep_w<<<128, 256, 0, stream>>>(Wout, bout, colsum, colsumsq,
                                  gamma, beta, woutb, badj + 8 * 256, 2560);
  gemm_stage<<<dim3(1, 128), 256, 0, stream>>>(feats, woutb, badj + 8 * 256,
                                               nullptr, out, 2560, nullptr, nullptr, 0);
}